// Round 3
// baseline (341.559 us; speedup 1.0000x reference)
//
#include <hip/hip_runtime.h>
#include <hip/hip_bf16.h>

// Flash attention fwd, [4,16,2048,128] fp32 -> fp32.
// v6: occupancy attack. global_load_lds staging (no reg round-trip, -32 VGPR),
// pre-swizzled global source + XOR-swizzled LDS reads (G21), split QK^T chains
// to halve score-reg liveness, __launch_bounds__(256,3) -> 3 blocks/CU.
// K single-buffered (16KB) + V double-buffered (32KB) = 49152 B LDS.
// No-max softmax (p=exp2(s)), v_perm bf16 pack, S^T formulation, sigma(V).
//
// ws: Kb (bf16) | Vt (bf16, [bh][d][sigma(s)])

#define S_LEN  2048
#define D_HEAD 128
#define BH     64
#define BM     128         // per block: 4 waves x 32 q-rows
#define BN     64          // keys per iteration
#define NITER  (S_LEN / BN)
#define ELEMS  (4 * 16 * 2048 * 128)

typedef __attribute__((ext_vector_type(8)))  short    bfrag8;
typedef __attribute__((ext_vector_type(16))) float    f32x16;
typedef __attribute__((ext_vector_type(4)))  float    f32x4;
typedef __attribute__((ext_vector_type(4)))  unsigned u32x4;

static __device__ __forceinline__ short f2bf(float x) {
    return __builtin_bit_cast(short, __float2bfloat16(x));
}
// truncating pack: (bf16(lo)) | (bf16(hi)<<16), one v_perm_b32
static __device__ __forceinline__ unsigned pk2t(float lo, float hi) {
    return __builtin_amdgcn_perm(__builtin_bit_cast(unsigned, hi),
                                 __builtin_bit_cast(unsigned, lo), 0x07060302u);
}

// async global->LDS, 16 B per lane; LDS dest = wave-uniform base + lane*16
#define GLL16(gp, lp) __builtin_amdgcn_global_load_lds( \
    (const __attribute__((address_space(1))) unsigned*)(gp), \
    (__attribute__((address_space(3))) unsigned*)(lp), 16, 0, 0)

// ---------------- fused prepass ----------------
// blocks [0,1024): V transpose, tile = 128 keys x 128 d, sigma baked in LDS store,
//                  write side emits full 256 B contiguous row segments.
// blocks [1024,2048): K fp32->bf16, grid-strided 16384 elems/block.
// sigma = swap bits 2,3 of key index (16-local), involution.
__global__ __launch_bounds__(256) void prepass(
        const float* __restrict__ K, const float* __restrict__ V,
        short* __restrict__ Kb, short* __restrict__ Vt) {
    __shared__ short sTT[128][136];   // 34816 B, pad keeps b128 reads 2-way
    const int tid = threadIdx.x;
    const int bid = blockIdx.x;
    if (bid < 1024) {
        const int bh = bid >> 4;
        const int k0 = (bid & 15) * 128;
        const float* src = V + ((size_t)bh * S_LEN + k0) * D_HEAD;
        {   // read 128 keys x 128 d fp32; store bf16 transposed at sigma(key)
            const int k  = tid >> 1;
            const int c  = (tid & 1) * 64;
            const int sk = (k & ~12) | ((k & 4) << 1) | ((k & 8) >> 1);
            const float* p = src + (size_t)k * D_HEAD + c;
            #pragma unroll
            for (int i = 0; i < 16; ++i) {
                float4 a = *(const float4*)(p + i * 4);
                sTT[c + i*4 + 0][sk] = f2bf(a.x);
                sTT[c + i*4 + 1][sk] = f2bf(a.y);
                sTT[c + i*4 + 2][sk] = f2bf(a.z);
                sTT[c + i*4 + 3][sk] = f2bf(a.w);
            }
        }
        __syncthreads();
        {   // write: wave covers 4 rows x 256 B fully-contiguous per instr
            const int c16 = tid & 15;
            #pragma unroll
            for (int it = 0; it < 8; ++it) {
                int d = it * 16 + (tid >> 4);
                bfrag8 t = *(const bfrag8*)&sTT[d][c16 * 8];
                *(bfrag8*)(Vt + ((size_t)bh * D_HEAD + d) * S_LEN + k0 + c16 * 8) = t;
            }
        }
    } else {
        const int chunk = bid - 1024;
        #pragma unroll
        for (int it = 0; it < 8; ++it) {
            size_t idx = ((size_t)chunk * 8 + it) * 2048 + (size_t)tid * 8;
            float4 a = *(const float4*)(K + idx);
            float4 b = *(const float4*)(K + idx + 4);
            bfrag8 t;
            t[0]=f2bf(a.x); t[1]=f2bf(a.y); t[2]=f2bf(a.z); t[3]=f2bf(a.w);
            t[4]=f2bf(b.x); t[5]=f2bf(b.y); t[6]=f2bf(b.z); t[7]=f2bf(b.w);
            *(bfrag8*)(Kb + idx) = t;
        }
    }
}

// ---------------- main flash attention ----------------
__global__ __launch_bounds__(256, 3) void attn_kernel(
        const float* __restrict__ Q, const short* __restrict__ Kb,
        const short* __restrict__ Vt, float* __restrict__ Out) {
    // LDS: sK [0,16384): 64 keys x 128 d, 16B-unit col XOR-swizzled by (key&15).
    //      sV dbuf [16384,49152): 2 x (128 d x 64 keys), col XOR by (d&7).
    // 3 x 49152 = 147456 <= 163840 -> 3 blocks/CU (12 waves).
    // Epilogue aliases smem[0,33792) as per-wave f32 [16][132] transpose buffers.
    __shared__ __align__(16) char smem[49152];

    const int tid  = threadIdx.x;
    const int w    = tid >> 6;
    const int lane = tid & 63;
    const int l31  = lane & 31;
    const int e    = lane >> 5;

    // XCD-swizzle: all 16 q-tiles of one bh on one XCD (K/V L2 reuse).
    int bid = blockIdx.x + gridDim.x * blockIdx.y;
    int xcd = bid & 7;
    int j   = bid >> 3;
    int bh  = (j >> 4) * 8 + xcd;
    int qt  = j & 15;
    const int qm0 = qt * BM;
    const size_t base = (size_t)bh * S_LEN * D_HEAD;

    const short* kptr = Kb + base;
    const short* vptr = Vt + base;

    // per-lane pre-swizzled global source addresses (linear LDS dest).
    // K instr (w,p): keys p*16+w*4+(l>>4); lds = p*4096+w*1024+l*16.
    //   source col16 = (l&15) ^ (key&15); key&15 = (w*4+(l>>4))&15 (p-invariant).
    const int krow = w * 4 + (lane >> 4);
    const char* kgl = (const char*)kptr + krow * 256
                    + (((lane & 15) ^ (krow & 15)) << 4);
    // V instr (w,p): rows p*32+w*8+(l>>3); source col16 = (l&7) ^ (d&7), d&7 = l>>3.
    const int vrow = w * 8 + (lane >> 3);
    const char* vgl = (const char*)vptr + vrow * 4096
                    + (((lane & 7) ^ (lane >> 3)) << 4);
    char* ldsK = smem + w * 1024;            // + p*4096
    char* ldsV = smem + 16384 + w * 1024;    // + buf*16384 + p*4096

    // issue tile-0 staging (async, direct to LDS)
    #pragma unroll
    for (int p = 0; p < 4; ++p) GLL16(kgl + p * 4096, ldsK + p * 4096);
    #pragma unroll
    for (int p = 0; p < 4; ++p) GLL16(vgl + p * 131072, ldsV + p * 4096);

    // Q -> regs (fp32 read, bf16 with log2e/sqrt(128) folded) during load flight
    bfrag8 qf[8];
    {
        const float QSCALE = 1.4426950408889634f * 0.08838834764831845f;
        const float* qrow = Q + base + (size_t)(qm0 + w * 32 + l31) * D_HEAD;
        #pragma unroll
        for (int ks = 0; ks < 8; ++ks) {
            float4 a = *(const float4*)(qrow + ks * 16 + e * 8);
            float4 b = *(const float4*)(qrow + ks * 16 + e * 8 + 4);
            bfrag8 t;
            t[0] = f2bf(a.x * QSCALE); t[1] = f2bf(a.y * QSCALE);
            t[2] = f2bf(a.z * QSCALE); t[3] = f2bf(a.w * QSCALE);
            t[4] = f2bf(b.x * QSCALE); t[5] = f2bf(b.y * QSCALE);
            t[6] = f2bf(b.z * QSCALE); t[7] = f2bf(b.w * QSCALE);
            qf[ks] = t;
        }
    }

    f32x16 of[4];
    #pragma unroll
    for (int nt = 0; nt < 4; ++nt)
        #pragma unroll
        for (int r = 0; r < 16; ++r) of[nt][r] = 0.f;
    float lsum = 0.f;

    // swizzled LDS read bases: addr = base ^ (idx<<5) reproduces col^(row&mask).
    const int kb      = l31 * 256 + (((l31 & 15) ^ e) << 4);
    const int vb_lane = l31 * 128 + (((l31 & 7) ^ e) << 4);

    __syncthreads();   // staging complete (vmcnt drained by compiler)

    for (int kk = 0; kk < NITER; ++kk) {
        if (kk + 1 < NITER) {          // V(kk+1) -> other buffer; its previous
            const char* vg = vgl + (kk + 1) * 128;   // readers fenced 1 tile ago
            char* lv = ldsV + (((kk + 1) & 1) << 14);
            #pragma unroll
            for (int p = 0; p < 4; ++p) GLL16(vg + p * 131072, lv + p * 4096);
        }

        // S^T rows 0..31 = K(0..31) . Q^T
        f32x16 st0;
        #pragma unroll
        for (int r = 0; r < 16; ++r) st0[r] = 0.f;
        __builtin_amdgcn_s_setprio(1);
        #pragma unroll
        for (int ks = 0; ks < 8; ++ks) {
            bfrag8 a0 = *(const bfrag8*)(smem + (kb ^ (ks << 5)));
            st0 = __builtin_amdgcn_mfma_f32_32x32x16_bf16(a0, qf[ks], st0, 0, 0, 0);
        }
        __builtin_amdgcn_s_setprio(0);

        unsigned pb0[8], pb1[8];
        float psum = 0.f;
        #pragma unroll
        for (int r2 = 0; r2 < 8; ++r2) {   // p = exp2(s), scale-invariant softmax
            float a = __builtin_amdgcn_exp2f(st0[2 * r2]);
            float b = __builtin_amdgcn_exp2f(st0[2 * r2 + 1]);
            psum += a + b;
            pb0[r2] = pk2t(a, b);
        }

        // S^T rows 32..63 (same swizzle: (32+l31)&15 == l31&15)
        f32x16 st1;
        #pragma unroll
        for (int r = 0; r < 16; ++r) st1[r] = 0.f;
        __builtin_amdgcn_s_setprio(1);
        #pragma unroll
        for (int ks = 0; ks < 8; ++ks) {
            bfrag8 a1 = *(const bfrag8*)(smem + 8192 + (kb ^ (ks << 5)));
            st1 = __builtin_amdgcn_mfma_f32_32x32x16_bf16(a1, qf[ks], st1, 0, 0, 0);
        }
        __builtin_amdgcn_s_setprio(0);

        __syncthreads();               // all sK reads done; V prefetch drained

        if (kk + 1 < NITER) {          // K(kk+1) -> sK (safe: QK^T complete);
            const char* kg = kgl + (kk + 1) * 16384;   // covered by exp+PV
            #pragma unroll
            for (int p = 0; p < 4; ++p) GLL16(kg + p * 4096, ldsK + p * 4096);
        }

        #pragma unroll
        for (int r2 = 0; r2 < 8; ++r2) {
            float a = __builtin_amdgcn_exp2f(st1[2 * r2]);
            float b = __builtin_amdgcn_exp2f(st1[2 * r2 + 1]);
            psum += a + b;
            pb1[r2] = pk2t(a, b);
        }
        lsum += psum;

        // O^T += V^T . P   (reads current V buffer)
        const int vb = 16384 + ((kk & 1) << 14) + vb_lane;
        __builtin_amdgcn_s_setprio(1);
        #pragma unroll
        for (int s = 0; s < 4; ++s) {
            const unsigned* pb = (s >> 1) ? pb1 : pb0;
            const int u = s & 1;
            u32x4 uu; uu[0]=pb[4*u]; uu[1]=pb[4*u+1]; uu[2]=pb[4*u+2]; uu[3]=pb[4*u+3];
            bfrag8 bfr = __builtin_bit_cast(bfrag8, uu);
            const int va = vb ^ (s << 5);
            #pragma unroll
            for (int nt = 0; nt < 4; ++nt) {
                bfrag8 av = *(const bfrag8*)(smem + va + nt * 4096);
                of[nt] = __builtin_amdgcn_mfma_f32_32x32x16_bf16(av, bfr, of[nt], 0, 0, 0);
            }
        }
        __builtin_amdgcn_s_setprio(0);

        __syncthreads();               // PV reads done; K prefetch drained
    }

    // epilogue: reduce l across halves, normalize, transpose O^T->O via LDS, store.
    lsum += __shfl_xor(lsum, 32);
    float inv = 1.0f / lsum;
    #pragma unroll
    for (int nt = 0; nt < 4; ++nt)
        #pragma unroll
        for (int r = 0; r < 16; ++r) of[nt][r] *= inv;

    float* sO = (float*)smem + w * 2112;   // per-wave [16][132] f32 (33792 B total)
    const int hbit = (lane >> 4) & 1;
    __syncthreads();
    #pragma unroll
    for (int h = 0; h < 2; ++h) {
        if (hbit == h) {
            int q16 = l31 & 15;
            #pragma unroll
            for (int nt = 0; nt < 4; ++nt)
                #pragma unroll
                for (int c = 0; c < 4; ++c) {
                    f32x4 wv;
                    wv[0] = of[nt][4*c]; wv[1] = of[nt][4*c+1];
                    wv[2] = of[nt][4*c+2]; wv[3] = of[nt][4*c+3];
                    *(f32x4*)&sO[q16 * 132 + nt * 32 + c * 8 + e * 4] = wv;
                }
        }
        __syncthreads();
        #pragma unroll
        for (int i = 0; i < 8; ++i) {
            int qloc = i * 2 + e;
            f32x4 v = *(const f32x4*)&sO[qloc * 132 + 4 * l31];
            *(f32x4*)(Out + base + (size_t)(qm0 + w * 32 + h * 16 + qloc) * D_HEAD + 4 * l31) = v;
        }
        __syncthreads();
    }
}

extern "C" void kernel_launch(void* const* d_in, const int* in_sizes, int n_in,
                              void* d_out, int out_size, void* d_ws, size_t ws_size,
                              hipStream_t stream) {
    const float* Q = (const float*)d_in[0];
    const float* K = (const float*)d_in[1];
    const float* V = (const float*)d_in[2];
    float* Out = (float*)d_out;

    short* Kb = (short*)d_ws;
    short* Vt = Kb + (size_t)ELEMS;

    prepass<<<dim3(2048), 256, 0, stream>>>(K, V, Kb, Vt);
    attn_kernel<<<dim3(S_LEN / BM, BH), 256, 0, stream>>>(Q, Kb, Vt, Out);
}